// Round 8
// baseline (143.115 us; speedup 1.0000x reference)
//
#include <hip/hip_runtime.h>

namespace {

constexpr int IMG = 512;
constexpr int PH  = 8;     // per-thread output rows
constexpr int BW_ = 256;   // block output width  (64 lanes x 4 floats)
constexpr int BH_ = 32;    // block output height (4 waves x 8 rows)

__device__ __forceinline__ int clampi(int v, int lo, int hi) {
    return v < lo ? lo : (v > hi ? hi : v);
}

__global__ __launch_bounds__(256)
void gauss_blur_kernel(const float* __restrict__ in, float* __restrict__ out) {
    const float KW[9] = {
        1.3383062e-4f, 4.4318616e-3f, 5.3990966e-2f, 2.4197144e-1f,
        3.9894347e-1f, 2.4197144e-1f, 5.3990966e-2f, 4.4318616e-3f,
        1.3383062e-4f};

    const int tid  = threadIdx.x;
    const int lane = tid & 63;
    const int wave = tid >> 6;
    const int b    = blockIdx.z;
    const int x0   = blockIdx.x * BW_ + 4 * lane;   // this thread's output x
    const int y0   = blockIdx.y * BH_ + wave * PH;  // this thread's first output y

    const float* __restrict__ inb = in + (size_t)b * IMG * IMG;

    const bool edgeL = (x0 == 0);          // window [x0-4,x0) fully clamped to col 0
    const bool edgeR = (x0 + 4 == IMG);    // window [x0+4,x0+8) fully clamped to col 511

    // Ring buffer of raw rows: [r % 3][left, center, right]
    float4 raw[3][3];

    auto load_row = [&](int r, int slot) {
        const int gy = clampi(y0 - 4 + r, 0, IMG - 1);
        const float* rp = inb + (size_t)gy * IMG;
        raw[slot][1] = *reinterpret_cast<const float4*>(rp + x0);
        if (edgeL) { const float e = rp[0];       raw[slot][0] = make_float4(e, e, e, e); }
        else       { raw[slot][0] = *reinterpret_cast<const float4*>(rp + x0 - 4); }
        if (edgeR) { const float e = rp[IMG - 1]; raw[slot][2] = make_float4(e, e, e, e); }
        else       { raw[slot][2] = *reinterpret_cast<const float4*>(rp + x0 + 4); }
    };

    load_row(0, 0);
    load_row(1, 1);
    load_row(2, 2);

    float4 acc[PH] = {};

    #pragma unroll
    for (int r = 0; r < PH + 8; ++r) {
        const int slot = r % 3;  // static after unroll

        // Pull the staged row into the 12-float window (register moves; frees
        // the ring slot so the prefetch below can issue immediately).
        const float w[12] = {
            raw[slot][0].x, raw[slot][0].y, raw[slot][0].z, raw[slot][0].w,
            raw[slot][1].x, raw[slot][1].y, raw[slot][1].z, raw[slot][1].w,
            raw[slot][2].x, raw[slot][2].y, raw[slot][2].z, raw[slot][2].w};

        // Prefetch row r+3 into the freed slot (consumed 3 iterations later).
        if (r + 3 < PH + 8) load_row(r + 3, slot);

        // Horizontal 9-tap for this row.
        float h0 = 0.f, h1 = 0.f, h2 = 0.f, h3 = 0.f;
        #pragma unroll
        for (int t = 0; t < 9; ++t) {
            h0 = fmaf(KW[t], w[t + 0], h0);
            h1 = fmaf(KW[t], w[t + 1], h1);
            h2 = fmaf(KW[t], w[t + 2], h2);
            h3 = fmaf(KW[t], w[t + 3], h3);
        }

        // Vertical accumulate: h-row r feeds output rows rr with r-rr in [0,8].
        #pragma unroll
        for (int rr = 0; rr < PH; ++rr) {
            const int k = r - rr;
            if (k >= 0 && k < 9) {
                acc[rr].x = fmaf(KW[k], h0, acc[rr].x);
                acc[rr].y = fmaf(KW[k], h1, acc[rr].y);
                acc[rr].z = fmaf(KW[k], h2, acc[rr].z);
                acc[rr].w = fmaf(KW[k], h3, acc[rr].w);
            }
        }
    }

    float* __restrict__ outb = out + (size_t)b * IMG * IMG;
    #pragma unroll
    for (int rr = 0; rr < PH; ++rr) {
        *reinterpret_cast<float4*>(&outb[(size_t)(y0 + rr) * IMG + x0]) = acc[rr];
    }
}

}  // namespace

extern "C" void kernel_launch(void* const* d_in, const int* in_sizes, int n_in,
                              void* d_out, int out_size, void* d_ws, size_t ws_size,
                              hipStream_t stream) {
    const float* x = (const float*)d_in[0];
    float* out = (float*)d_out;

    const int batch = in_sizes[0] / (IMG * IMG);  // 128

    dim3 grid(IMG / BW_, IMG / BH_, batch);       // (2, 16, 128) = 4096 blocks
    gauss_blur_kernel<<<grid, 256, 0, stream>>>(x, out);
}

// Round 9
// 69.368 us; speedup vs baseline: 2.0631x; 2.0631x over previous
//
#include <hip/hip_runtime.h>
#include <stdint.h>

namespace {

constexpr int IMG   = 512;
constexpr int TSX   = 64;          // strip width (outputs)
constexpr int STEP  = 32;          // output rows per step
constexpr int RAWR  = STEP + 8;    // 40 raw/h rows per step
constexpr int RSTR  = 76;          // raw row: [halo_l 4f | main 64f | halo_r 8f]
constexpr int NCH   = 12;          // DMA chunks (64 f4 = 1 KB) per step: 760 f4 + pad
constexpr int RBUF  = NCH * 256;   // 3072 floats per raw buffer
constexpr int HSTR  = 68;          // h-buffer row stride
constexpr int NSTEP = IMG / STEP;  // 16

__device__ __forceinline__ int clampi(int v, int lo, int hi) {
    return v < lo ? lo : (v > hi ? hi : v);
}

__global__ __launch_bounds__(256)
void gauss_blur_kernel(const float* __restrict__ in, float* __restrict__ out) {
    const float KW[9] = {
        1.3383062e-4f, 4.4318616e-3f, 5.3990966e-2f, 2.4197144e-1f,
        3.9894347e-1f, 2.4197144e-1f, 5.3990966e-2f, 4.4318616e-3f,
        1.3383062e-4f};

    __shared__ float s_raw[2][RBUF];     // 2 x 12288 B raw rows (double buffer)
    __shared__ float s_h[RAWR * HSTR];   // 40 x 64 h-pass rows (10880 B)

    const int tid  = threadIdx.x;
    const int lane = tid & 63;
    const int wave = tid >> 6;
    const int bx   = blockIdx.x;         // x-strip 0..7
    const int b    = blockIdx.y;         // image
    const int tx0  = bx * TSX;
    const bool isL = (bx == 0);
    const bool isR = (bx == (IMG / TSX) - 1);

    const float* __restrict__ inb  = in  + (size_t)b * IMG * IMG;
    float* __restrict__       outb = out + (size_t)b * IMG * IMG;

    // Issue the 12 DMA chunks staging raw rows [32*tk-4, 32*tk+36) into buf.
    // Per-lane SOURCE address encodes (row,col) layout + y-clamp; LDS dest is
    // wave-uniform base + lane*16 (lane-linear). 3 chunks per wave.
    auto issue = [&](int tk, int buf) {
        #pragma unroll
        for (int c = 0; c < 3; ++c) {
            const int q  = wave * 3 + c;            // chunk 0..11
            const int f  = (q << 6) | lane;         // flat f4 slot
            unsigned ru  = (unsigned)f / 19u;       // raw row
            const int cf = f - 19 * (int)ru;        // f4 col 0..18
            int r = (int)ru; if (r > RAWR - 1) r = RAWR - 1;   // pad tail
            const int gy = clampi(STEP * tk - 4 + r, 0, IMG - 1);
            int gx = tx0 - 4 + 4 * cf;
            gx = clampi(gx, 0, IMG - 4);            // edge strips fixed up later
            const float* src = inb + (size_t)gy * IMG + gx;
            __builtin_amdgcn_global_load_lds(
                (const __attribute__((address_space(1))) uint32_t*)src,
                (__attribute__((address_space(3))) uint32_t*)(&s_raw[buf][0] + (q << 8)),
                16, 0, 0);
        }
    };

    issue(0, 0);   // prologue: stage tile 0

    #pragma unroll 1
    for (int k = 0; k < NSTEP; ++k) {
        const int buf = k & 1;

        // ---- stage next tile, then counted wait: drains tile k's DMA (and
        // last step's stores) while tile k+1's 3 chunks stay in flight ----
        if (k + 1 < NSTEP) {
            issue(k + 1, buf ^ 1);
            asm volatile("s_waitcnt vmcnt(3)" ::: "memory");
        } else {
            asm volatile("s_waitcnt vmcnt(0)" ::: "memory");
        }
        __builtin_amdgcn_sched_barrier(0);
        __builtin_amdgcn_s_barrier();            // B1: tile k staged; s_h free

        // ---- x-edge fixup (2/8 blocks): splat clamped halo columns ----
        if (isL | isR) {
            for (int t = tid; t < RAWR; t += 256) {
                float* row = &s_raw[buf][t * RSTR];
                if (isL) {                       // halo_l = splat x[0] (at c=4)
                    const float e = row[4];
                    float4 s = {e, e, e, e};
                    *reinterpret_cast<float4*>(&row[0]) = s;
                } else {                         // halo_r = splat x[511] (at c=67)
                    const float e = row[67];
                    float4 s = {e, e, e, e};
                    *reinterpret_cast<float4*>(&row[68]) = s;
                    *reinterpret_cast<float4*>(&row[72]) = s;
                }
            }
        }
        asm volatile("s_waitcnt lgkmcnt(0)" ::: "memory");
        __builtin_amdgcn_sched_barrier(0);
        __builtin_amdgcn_s_barrier();            // B2: fixup visible

        // ---- h-pass: 40 rows x 16 f4; contiguous 12-float windows ----
        for (int i = tid; i < RAWR * 16; i += 256) {
            const int r = i >> 4, j = i & 15;
            const float* rp = &s_raw[buf][r * RSTR + 4 * j];
            float4 a  = *reinterpret_cast<const float4*>(rp);
            float4 bq = *reinterpret_cast<const float4*>(rp + 4);
            float4 cq = *reinterpret_cast<const float4*>(rp + 8);
            const float w[12] = {a.x, a.y, a.z, a.w, bq.x, bq.y, bq.z, bq.w,
                                 cq.x, cq.y, cq.z, cq.w};
            float a0 = 0.f, a1 = 0.f, a2 = 0.f, a3 = 0.f;
            #pragma unroll
            for (int t = 0; t < 9; ++t) {
                a0 = fmaf(KW[t], w[t + 0], a0);
                a1 = fmaf(KW[t], w[t + 1], a1);
                a2 = fmaf(KW[t], w[t + 2], a2);
                a3 = fmaf(KW[t], w[t + 3], a3);
            }
            float4 o = {a0, a1, a2, a3};
            *reinterpret_cast<float4*>(&s_h[r * HSTR + 4 * j]) = o;
        }
        asm volatile("s_waitcnt lgkmcnt(0)" ::: "memory");
        __builtin_amdgcn_sched_barrier(0);
        __builtin_amdgcn_s_barrier();            // B3: s_h complete

        // ---- v-pass in registers: 4-wide x 2-tall patches, store ----
        const int px  = tid & 15;
        const int py  = tid >> 4;
        const int lx  = 4 * px;
        const int oy0 = 2 * py;                  // 0..30

        float4 acc0 = {0.f, 0.f, 0.f, 0.f};
        float4 acc1 = {0.f, 0.f, 0.f, 0.f};
        #pragma unroll
        for (int t = 0; t < 10; ++t) {
            float4 h = *reinterpret_cast<const float4*>(&s_h[(oy0 + t) * HSTR + lx]);
            if (t < 9) {
                acc0.x = fmaf(KW[t], h.x, acc0.x);
                acc0.y = fmaf(KW[t], h.y, acc0.y);
                acc0.z = fmaf(KW[t], h.z, acc0.z);
                acc0.w = fmaf(KW[t], h.w, acc0.w);
            }
            if (t >= 1) {
                acc1.x = fmaf(KW[t - 1], h.x, acc1.x);
                acc1.y = fmaf(KW[t - 1], h.y, acc1.y);
                acc1.z = fmaf(KW[t - 1], h.z, acc1.z);
                acc1.w = fmaf(KW[t - 1], h.w, acc1.w);
            }
        }
        const int y = STEP * k + oy0;
        *reinterpret_cast<float4*>(&outb[(size_t)y * IMG + tx0 + lx])       = acc0;
        *reinterpret_cast<float4*>(&outb[(size_t)(y + 1) * IMG + tx0 + lx]) = acc1;
        // next iteration's B1 separates these v-pass reads from the next
        // h-pass writes to s_h, and the raw buffer k reads finished at B3.
    }
}

}  // namespace

extern "C" void kernel_launch(void* const* d_in, const int* in_sizes, int n_in,
                              void* d_out, int out_size, void* d_ws, size_t ws_size,
                              hipStream_t stream) {
    const float* x = (const float*)d_in[0];
    float* out = (float*)d_out;

    const int batch = in_sizes[0] / (IMG * IMG);  // 128

    dim3 grid(IMG / TSX, batch);                  // (8, 128) = 1024 blocks
    gauss_blur_kernel<<<grid, 256, 0, stream>>>(x, out);
}

// Round 10
// 64.950 us; speedup vs baseline: 2.2035x; 1.0680x over previous
//
#include <hip/hip_runtime.h>

namespace {

constexpr int IMG   = 512;
constexpr int TSX   = 64;          // strip width
constexpr int STEP  = 32;          // output rows per step
constexpr int HR    = STEP + 8;    // 40 h-rows per step
constexpr int HSTR  = 68;          // s_h row stride (floats) — proven cheap
constexpr int NSTEP = IMG / STEP;  // 16
constexpr int NITEM = HR * 16;     // 640 h-items per step

__device__ __forceinline__ int clampi(int v, int lo, int hi) {
    return v < lo ? lo : (v > hi ? hi : v);
}

__global__ __launch_bounds__(256)
void gauss_blur_kernel(const float* __restrict__ in, float* __restrict__ out) {
    const float KW[9] = {
        1.3383062e-4f, 4.4318616e-3f, 5.3990966e-2f, 2.4197144e-1f,
        3.9894347e-1f, 2.4197144e-1f, 5.3990966e-2f, 4.4318616e-3f,
        1.3383062e-4f};

    __shared__ float s_h[HR * HSTR];   // 10880 B — the ONLY LDS buffer

    const int tid = threadIdx.x;
    const int bx  = blockIdx.x;        // x-strip 0..7
    const int b   = blockIdx.y;        // image
    const int tx0 = bx * TSX;
    const bool blkL = (bx == 0);
    const bool blkR = (bx == (IMG / TSX) - 1);

    const float* __restrict__ inb  = in  + (size_t)b * IMG * IMG;
    float* __restrict__       outb = out + (size_t)b * IMG * IMG;

    // v-pass geometry (fixed per thread)
    const int px  = tid & 15;
    const int py  = tid >> 4;
    const int lx  = 4 * px;
    const int oy0 = 2 * py;

    #pragma unroll 1
    for (int k = 0; k < NSTEP; ++k) {
        const int ybase = STEP * k - 4;

        // ---- phase A: horizontal 9-tap, global -> s_h ----
        // Batch-issue ALL loads first (9 per thread, branch-free addresses,
        // static register indexing), then compute. Item i: h-row r=i>>4,
        // f4-col j=i&15; window = floats [gxm, gxm+12) with gxm = tx0-4+4j.
        float4 L[3][3];
        #pragma unroll
        for (int it = 0; it < 3; ++it) {
            const int i = tid + 256 * it;
            if (i < NITEM) {                       // wave-uniform tail
                const int r   = i >> 4;
                const int j   = i & 15;
                const int gy  = clampi(ybase + r, 0, IMG - 1);
                const int gxm = tx0 - 4 + 4 * j;
                const float* rp = inb + (size_t)gy * IMG;
                L[it][0] = *reinterpret_cast<const float4*>(rp + clampi(gxm,     0, IMG - 4));
                L[it][1] = *reinterpret_cast<const float4*>(rp + clampi(gxm + 4, 0, IMG - 4));
                L[it][2] = *reinterpret_cast<const float4*>(rp + clampi(gxm + 8, 0, IMG - 4));
            }
        }
        #pragma unroll
        for (int it = 0; it < 3; ++it) {
            const int i = tid + 256 * it;
            if (i < NITEM) {
                const int r = i >> 4;
                const int j = i & 15;
                // Edge semantics: left strip j==0 -> w[0..3] = splat x[0];
                // right strip j==15 -> w[8..11] = splat x[511]. Predicated, no branch.
                float4 lf = L[it][0], md = L[it][1], rt = L[it][2];
                if (blkL && j == 0)  { const float e = lf.x; lf = make_float4(e, e, e, e); }
                if (blkR && j == 15) { const float e = rt.w; rt = make_float4(e, e, e, e); }
                const float w[12] = {lf.x, lf.y, lf.z, lf.w,
                                     md.x, md.y, md.z, md.w,
                                     rt.x, rt.y, rt.z, rt.w};
                float a0 = 0.f, a1 = 0.f, a2 = 0.f, a3 = 0.f;
                #pragma unroll
                for (int t = 0; t < 9; ++t) {
                    a0 = fmaf(KW[t], w[t + 0], a0);
                    a1 = fmaf(KW[t], w[t + 1], a1);
                    a2 = fmaf(KW[t], w[t + 2], a2);
                    a3 = fmaf(KW[t], w[t + 3], a3);
                }
                float4 o = {a0, a1, a2, a3};
                *reinterpret_cast<float4*>(&s_h[r * HSTR + 4 * j]) = o;
            }
        }
        __syncthreads();                           // s_h complete

        // ---- phase B: vertical 9-tap in registers, 4-wide x 2-tall ----
        float4 acc0 = {0.f, 0.f, 0.f, 0.f};
        float4 acc1 = {0.f, 0.f, 0.f, 0.f};
        #pragma unroll
        for (int t = 0; t < 10; ++t) {
            float4 h = *reinterpret_cast<const float4*>(&s_h[(oy0 + t) * HSTR + lx]);
            if (t < 9) {
                acc0.x = fmaf(KW[t], h.x, acc0.x);
                acc0.y = fmaf(KW[t], h.y, acc0.y);
                acc0.z = fmaf(KW[t], h.z, acc0.z);
                acc0.w = fmaf(KW[t], h.w, acc0.w);
            }
            if (t >= 1) {
                acc1.x = fmaf(KW[t - 1], h.x, acc1.x);
                acc1.y = fmaf(KW[t - 1], h.y, acc1.y);
                acc1.z = fmaf(KW[t - 1], h.z, acc1.z);
                acc1.w = fmaf(KW[t - 1], h.w, acc1.w);
            }
        }
        const int y = STEP * k + oy0;
        *reinterpret_cast<float4*>(&outb[(size_t)y * IMG + tx0 + lx])       = acc0;
        *reinterpret_cast<float4*>(&outb[(size_t)(y + 1) * IMG + tx0 + lx]) = acc1;
        __syncthreads();                           // s_h reads done before next step's writes
    }
}

}  // namespace

extern "C" void kernel_launch(void* const* d_in, const int* in_sizes, int n_in,
                              void* d_out, int out_size, void* d_ws, size_t ws_size,
                              hipStream_t stream) {
    const float* x = (const float*)d_in[0];
    float* out = (float*)d_out;

    const int batch = in_sizes[0] / (IMG * IMG);  // 128

    dim3 grid(IMG / TSX, batch);                  // (8, 128) = 1024 blocks
    gauss_blur_kernel<<<grid, 256, 0, stream>>>(x, out);
}